// Round 5
// baseline (526.223 us; speedup 1.0000x reference)
//
#include <hip/hip_runtime.h>
#include <math.h>

// GATv2 2-layer: N=50000, E=800000, HEADS=8, C=32, ODIM=256, IN_C=64
#define HEADS 8
#define CDIM 32
#define ODIM 256
#define BKT_SHIFT 7              // 128 nodes per bucket
#define CHUNK 2048               // edges per histogram chunk

typedef _Float16 h2 __attribute__((ext_vector_type(2)));
typedef _Float16 h4 __attribute__((ext_vector_type(4)));
typedef _Float16 h8 __attribute__((ext_vector_type(8)));
typedef float f32x4 __attribute__((ext_vector_type(4)));
union H4 { h4 v; h2 p[2]; };

#if __has_builtin(__builtin_amdgcn_fdot2)
#define FDOT2(a,b,c) __builtin_amdgcn_fdot2((a),(b),(c),false)
#else
static __device__ __forceinline__ float fdot2_sw(h2 a, h2 b, float c){
  return fmaf((float)a.x, (float)b.x, fmaf((float)a.y, (float)b.y, c));
}
#define FDOT2(a,b,c) fdot2_sw((a),(b),(c))
#endif

__device__ __forceinline__ float lrelu(float v, float s){ return fmaxf(v, s*v); }

// ================= atomic-free CSR build (bucket counting sort) =================
// R2: 800K device-scope atomicAdd = 72us floor -> LDS-only 5-pass sort (R3),
// hist fused into gemm1 grid (R4).

// pass 2: per-bucket exclusive scan over chunks (hist -> offs in-place)
__global__ __launch_bounds__(512) void csr_offs_kernel(
    int* __restrict__ hist, int* __restrict__ btotal, int NB, int B){
  __shared__ int s[512];
  int b = blockIdx.x, t = threadIdx.x;
  int v = (t < NB) ? hist[t*B + b] : 0;
  s[t] = v;
  __syncthreads();
  for (int off=1; off<512; off<<=1){
    int u = (t >= off) ? s[t-off] : 0;
    __syncthreads(); s[t] += u; __syncthreads();
  }
  int excl = s[t] - v;
  if (t < NB) hist[t*B + b] = excl;      // becomes offs[chunk][bucket]
  if (t == NB-1) btotal[b] = excl + v;
}

// pass 2b: bucket bases (exclusive scan of btotal, one block; B <= 512)
__global__ __launch_bounds__(512) void csr_base_kernel(
    const int* __restrict__ btotal, int* __restrict__ base, int B){
  __shared__ int s[512];
  int t = threadIdx.x;
  int v = (t < B) ? btotal[t] : 0;
  s[t] = v;
  __syncthreads();
  for (int off=1; off<512; off<<=1){
    int u = (t >= off) ? s[t-off] : 0;
    __syncthreads(); s[t] += u; __syncthreads();
  }
  if (t < B) base[t] = s[t] - v;
  if (t == B-1) base[B] = s[t];          // total valid edges
}

// pass 3: deterministic scatter to bucket-major packed array (no atomics)
__global__ __launch_bounds__(256) void csr_scatter_kernel(
    const int* __restrict__ src, const int* __restrict__ dst,
    const int* __restrict__ rank, const int* __restrict__ offs,
    const int* __restrict__ base, int* __restrict__ bpack, int e, int B){
  int t = threadIdx.x, k = blockIdx.x;
  int base_i = k*CHUNK;
#pragma unroll
  for (int j = 0; j < CHUNK/256; ++j){
    int i = base_i + j*256 + t;
    if (i < e){
      int r = rank[i];
      if (r >= 0){
        int d = dst[i], s = src[i];
        int b = d >> BKT_SHIFT;
        int pos = base[b] + offs[k*B + b] + r;
        bpack[pos] = (s << BKT_SHIFT) | (d & 127);   // s<2^16 -> fits 23 bits
      }
    }
  }
}

// pass 4: per-bucket counting sort -> csr (sequential writes) + indptr
__global__ __launch_bounds__(256) void csr_sort_kernel(
    const int* __restrict__ bpack, const int* __restrict__ base,
    int* __restrict__ csr, int* __restrict__ indptr, int n, int B){
  __shared__ int lh[128], cur[128], ss[128];
  int b = blockIdx.x, t = threadIdx.x;
  int beg = base[b], cnt = base[b+1] - beg;
  if (t < 128) lh[t] = 0;
  __syncthreads();
  for (int j = t; j < cnt; j += 256){
    int p = bpack[beg + j];
    atomicAdd(&lh[p & 127], 1);
  }
  __syncthreads();
  int v = (t < 128) ? lh[t] : 0;
  if (t < 128) ss[t] = v;
  __syncthreads();
  for (int off=1; off<128; off<<=1){
    int u = (t >= off && t < 128) ? ss[t-off] : 0;
    __syncthreads();
    if (t < 128) ss[t] += u;
    __syncthreads();
  }
  if (t < 128){
    int excl = ss[t] - v;
    cur[t] = excl;
    int node = (b << BKT_SHIFT) + t;
    if (node <= n) indptr[node] = beg + excl;   // node==n covered by last bucket
  }
  __syncthreads();
  for (int j = t; j < cnt; j += 256){
    int p = bpack[beg + j];
    int lpos = atomicAdd(&cur[p & 127], 1);
    csr[beg + lpos] = p >> BKT_SHIFT;
  }
}

// ---------------- MFMA GEMM: out[n,512] = X[n,K] * [Wl;Wr]^T + [bl;br] ----------------
// v_mfma_f32_16x16x32_f16; A=W (rows=channels), B=X (cols=nodes); C/D frag ->
// one contiguous h4 store/lane. X tile LDS fp16; W direct from global (L2-res).
// FUSE_HIST: y==2 slice (x < NB) runs the CSR bucket histogram concurrently.
template<int K, bool FUSE_HIST>
__global__ __launch_bounds__(256, 2) void gemm_mfma(const float* __restrict__ X,
    const float* __restrict__ Wl, const float* __restrict__ bl,
    const float* __restrict__ Wr, const float* __restrict__ br,
    _Float16* __restrict__ outl, _Float16* __restrict__ outr, int n,
    const int* __restrict__ src, const int* __restrict__ dst,
    int* __restrict__ rank, int* __restrict__ hist, int e, int B){
  if (FUSE_HIST && blockIdx.y == 2){
    int k = blockIdx.x;
    int NB = (e + CHUNK-1)/CHUNK;
    if (k >= NB) return;
    __shared__ int lh[512];
    int t = threadIdx.x;
    for (int b = t; b < B; b += 256) lh[b] = 0;
    __syncthreads();
    int base_i = k*CHUNK;
#pragma unroll
    for (int j = 0; j < CHUNK/256; ++j){
      int i = base_i + j*256 + t;
      if (i < e){
        int s = src[i], d = dst[i];
        int r = -1;
        if (s != d) r = atomicAdd(&lh[d>>BKT_SHIFT], 1);  // self-loops masked
        rank[i] = r;
      }
    }
    __syncthreads();
    for (int b = t; b < B; b += 256) hist[k*B + b] = lh[b];
    return;
  }
  const int KP = K + 8;
  __shared__ __align__(16) _Float16 Xs[64*(K+8)];
  int t = threadIdx.x;
  int n0 = blockIdx.x*64;
  int ybase = blockIdx.y;

  // stage X tile, fp32 -> fp16
  for (int idx = t; idx < 64*(K/4); idx += 256){
    int row = idx/(K/4), c = (idx%(K/4))*4;
    int node = n0 + row; if (node >= n) node = n-1;   // clamp; stores guarded
    float4 xv = *(const float4*)(X + (size_t)node*K + c);
    h4 hv = {(_Float16)xv.x, (_Float16)xv.y, (_Float16)xv.z, (_Float16)xv.w};
    *(h4*)(Xs + row*KP + c) = hv;
  }
  __syncthreads();

  int wave = t >> 6, lane = t & 63;
  int co = ybase*256 + wave*64;           // global channel base (0..511)
  const float* W   = (co < 256) ? Wl : Wr;
  const float* Bv  = (co < 256) ? bl : br;
  _Float16* outp   = (co < 256) ? outl : outr;
  int lco = co & 255;
  int lr = lane & 15, lg = lane >> 4;

  f32x4 acc[4][4];
#pragma unroll
  for (int c = 0; c < 4; ++c)
#pragma unroll
    for (int m = 0; m < 4; ++m) acc[c][m] = (f32x4){0.f, 0.f, 0.f, 0.f};

#pragma unroll
  for (int ks = 0; ks < K/32; ++ks){
    int k0 = ks*32 + lg*8;
    h8 a[4], b[4];
#pragma unroll
    for (int c = 0; c < 4; ++c){                 // A: W[ch][k0..k0+7], cvt f16
      const float* wp = W + (size_t)(lco + c*16 + lr)*K + k0;
      float4 w0 = *(const float4*)(wp);
      float4 w1 = *(const float4*)(wp + 4);
      a[c] = (h8){(_Float16)w0.x,(_Float16)w0.y,(_Float16)w0.z,(_Float16)w0.w,
                  (_Float16)w1.x,(_Float16)w1.y,(_Float16)w1.z,(_Float16)w1.w};
    }
#pragma unroll
    for (int m = 0; m < 4; ++m)                  // B: Xs[node][k0..k0+7]
      b[m] = *(const h8*)(Xs + (m*16 + lr)*KP + k0);
#pragma unroll
    for (int c = 0; c < 4; ++c)
#pragma unroll
      for (int m = 0; m < 4; ++m)
        acc[c][m] = __builtin_amdgcn_mfma_f32_16x16x32_f16(a[c], b[m], acc[c][m], 0, 0, 0);
  }

  // epilogue: frag (c,m): lane -> node n0+m*16+(lane&15), channels lco+c*16+lg*4+[0..3]
#pragma unroll
  for (int c = 0; c < 4; ++c){
    int ch = lco + c*16 + lg*4;
    float4 bb = *(const float4*)(Bv + ch);
#pragma unroll
    for (int m = 0; m < 4; ++m){
      int node = n0 + m*16 + lr;
      if (node < n){
        h4 o = {(_Float16)(acc[c][m][0] + bb.x), (_Float16)(acc[c][m][1] + bb.y),
                (_Float16)(acc[c][m][2] + bb.z), (_Float16)(acc[c][m][3] + bb.w)};
        *(h4*)(outp + (size_t)node*ODIM + ch) = o;
      }
    }
  }
}

// ---------------- head-partitioned edge softmax + aggregate ----------------
// R5: R4 showed fetch-path-bound (dur = FETCH/2.8TB/s, FETCH = 8 x 25.6MB:
// every XCD streams the whole xl through its 4MB L2 because gathers are
// random over a 25.6MB working set). Per-head slices are independent until
// the final mean, and head slice = 3.2MB fits one XCD's L2. head =
// blockIdx.x & 7 pins each head to one XCD (de-facto round-robin mapping;
// perf-only assumption). Wave = (node, head): 8 groups x 8 lanes, group g
// processes edge k+g, lane holds h4 (4 ch of the 32-ch head slice).
// Writes fp32 partials part[node][head][32]; mean+bias+act in head_reduce.
__global__ __launch_bounds__(256) void edge_head_kernel(
    const _Float16* __restrict__ xl, const _Float16* __restrict__ xr,
    const float* __restrict__ att,
    const int* __restrict__ indptr, const int* __restrict__ csr_src,
    float* __restrict__ part, int n)
{
  int head = blockIdx.x & 7;
  int node = ((blockIdx.x >> 3) << 2) + (threadIdx.x >> 6);
  if (node >= n) return;
  int lane = threadIdx.x & 63;
  int g = lane >> 3, q = lane & 7;
  const float LOG2E = 1.44269504088896341f;

  float4 attf = *(const float4*)(att + head*32 + 4*q);
  h2 at0 = (h2){(_Float16)(attf.x*LOG2E), (_Float16)(attf.y*LOG2E)};
  h2 at1 = (h2){(_Float16)(attf.z*LOG2E), (_Float16)(attf.w*LOG2E)};
  const h2 c02 = {(_Float16)0.2f, (_Float16)0.2f};

  const _Float16* xlh = xl + head*32 + 4*q;
  H4 xr4; xr4.v = *(const h4*)(xr + (size_t)node*ODIM + head*32 + 4*q);

  auto scoreh = [&](const H4& c)->float{
    h2 t0 = c.p[0] + xr4.p[0];
    h2 t1 = c.p[1] + xr4.p[1];
    h2 q0 = __builtin_elementwise_max(t0, t0 * c02);
    h2 q1 = __builtin_elementwise_max(t1, t1 * c02);
    float d = FDOT2(q0, at0, FDOT2(q1, at1, 0.f));
    d += __shfl_xor(d, 1);   // reduce over the 8 lanes of this group
    d += __shfl_xor(d, 2);
    d += __shfl_xor(d, 4);
    return d;
  };

  // self-loop seeds group 0 only (counted once after cross-group sum)
  H4 self; self.v = *(const h4*)(xlh + (size_t)node*ODIM);
  float w0 = exp2f(scoreh(self));
  float gz = (g == 0) ? w0 : 0.f;
  float denom = gz;
  float4 acc;
  acc.x = gz * (float)self.v.x;
  acc.y = gz * (float)self.v.y;
  acc.z = gz * (float)self.v.z;
  acc.w = gz * (float)self.v.w;

  int beg = __builtin_amdgcn_readfirstlane(indptr[node]);
  int end = __builtin_amdgcn_readfirstlane(indptr[node+1]);
  int cnt = end - beg;

  for (int cb = 0; cb < cnt; cb += 64){          // 64-edge chunks (deg>64 safe)
    int ccnt = min(cnt - cb, 64);
    int sidx = (lane < ccnt) ? csr_src[beg + cb + lane] : node;  // 256B wave read
#pragma unroll 2
    for (int k = 0; k < ccnt; k += 8){
      int j = k + g;
      int si = __shfl(sidx, j);                  // lanes j>=ccnt hold 'node' (safe)
      H4 cv; cv.v = *(const h4*)(xlh + (size_t)si*ODIM);   // 64B/group, L2-hot
      float sc = scoreh(cv);
      float pe = (j < ccnt) ? exp2f(sc) : 0.f;
      denom += pe;
      acc.x = fmaf(pe, (float)cv.v.x, acc.x);
      acc.y = fmaf(pe, (float)cv.v.y, acc.y);
      acc.z = fmaf(pe, (float)cv.v.z, acc.z);
      acc.w = fmaf(pe, (float)cv.v.w, acc.w);
    }
  }

  // cross-group sum (8 groups -> all lanes)
#pragma unroll
  for (int off = 8; off < 64; off <<= 1){
    denom += __shfl_xor(denom, off);
    acc.x += __shfl_xor(acc.x, off);
    acc.y += __shfl_xor(acc.y, off);
    acc.z += __shfl_xor(acc.z, off);
    acc.w += __shfl_xor(acc.w, off);
  }
  if (g == 0){
    float inv = 1.f/denom;
    float* pp = part + ((size_t)node*HEADS + head)*CDIM + 4*q;
    pp[0] = acc.x*inv; pp[1] = acc.y*inv; pp[2] = acc.z*inv; pp[3] = acc.w*inv;
  }
}

// mean over heads + bias (+ optional leaky relu)
__global__ __launch_bounds__(256) void head_reduce_kernel(
    const float* __restrict__ part, const float* __restrict__ bias,
    float* __restrict__ out, int n, int act){
  int idx = blockIdx.x*256 + threadIdx.x;       // one thread per (node, ch)
  int node = idx >> 5, c = idx & 31;
  if (node >= n) return;
  const float* p = part + (size_t)node*(HEADS*CDIM) + c;
  float s = p[0]+p[32]+p[64]+p[96]+p[128]+p[160]+p[192]+p[224];
  float o = s*0.125f + bias[c];
  if (act) o = lrelu(o, 0.01f);
  out[(size_t)node*CDIM + c] = o;
}

extern "C" void kernel_launch(void* const* d_in, const int* in_sizes, int n_in,
                              void* d_out, int out_size, void* d_ws, size_t ws_size,
                              hipStream_t stream){
  (void)n_in; (void)out_size; (void)ws_size;
  const float* x    = (const float*)d_in[0];
  const int*   ei   = (const int*)d_in[1];
  const float* W1l  = (const float*)d_in[2];
  const float* b1l  = (const float*)d_in[3];
  const float* W1r  = (const float*)d_in[4];
  const float* b1r  = (const float*)d_in[5];
  const float* att1 = (const float*)d_in[6];
  const float* bias1= (const float*)d_in[7];
  const float* W2l  = (const float*)d_in[8];
  const float* b2l  = (const float*)d_in[9];
  const float* W2r  = (const float*)d_in[10];
  const float* b2r  = (const float*)d_in[11];
  const float* att2 = (const float*)d_in[12];
  const float* bias2= (const float*)d_in[13];
  int n = in_sizes[0] / 64;   // 50000
  int e = in_sizes[1] / 2;    // 800000
  const int* src = ei;
  const int* dst = ei + e;

  char* ws = (char*)d_ws;
  size_t off = 0;
  auto alloc = [&](size_t bytes)->char*{
    char* p = ws + off; off += (bytes + 255) & ~(size_t)255; return p;
  };
  _Float16* xl  = (_Float16*)alloc((size_t)n*ODIM*2);  // 25.6 MB fp16
  _Float16* xr  = (_Float16*)alloc((size_t)n*ODIM*2);  // 25.6 MB fp16
  float* h      = (float*)alloc((size_t)n*CDIM*4);     // 6.4 MB layer-1 output
  float* part   = (float*)alloc((size_t)n*HEADS*CDIM*4); // 51.2 MB head partials
  int*   indptr = (int*)alloc((size_t)(n+1)*4);
  int*   rank   = (int*)alloc((size_t)e*4);
  int*   csr    = (int*)alloc((size_t)e*4);
  int*   bpack  = (int*)alloc((size_t)e*4);

  int NB = (e + CHUNK-1) / CHUNK;   // 391 edge chunks
  int B  = (n + 127) >> 7;          // 391 buckets of 128 nodes
  int*   hist   = (int*)alloc((size_t)NB*B*4);         // 611 KB (becomes offs)
  int*   btotal = (int*)alloc((size_t)B*4);
  int*   base   = (int*)alloc((size_t)(B+1)*4);

  int nt64 = (n + 63) / 64;         // 782
  int nq   = (n + 3) / 4;           // node quads
  int nrc  = (n*CDIM + 255) / 256;  // reduce blocks

  // ---- layer-1 GEMM with fused CSR histogram (y==2 slice) ----
  gemm_mfma<64,true><<<dim3(nt64,3), 256, 0, stream>>>(
      x, W1l, b1l, W1r, b1r, xl, xr, n, src, dst, rank, hist, e, B);
  // ---- rest of atomic-free CSR build ----
  csr_offs_kernel<<<B, 512, 0, stream>>>(hist, btotal, NB, B);
  csr_base_kernel<<<1, 512, 0, stream>>>(btotal, base, B);
  csr_scatter_kernel<<<NB, 256, 0, stream>>>(src, dst, rank, hist, base, bpack, e, B);
  csr_sort_kernel<<<B, 256, 0, stream>>>(bpack, base, csr, indptr, n, B);

  // ---- layer 1 edge phase (head-partitioned, XCD-pinned) ----
  edge_head_kernel<<<nq*8, 256, 0, stream>>>(xl, xr, att1, indptr, csr, part, n);
  head_reduce_kernel<<<nrc, 256, 0, stream>>>(part, bias1, h, n, 1);
  // ---- layer 2 ----
  gemm_mfma<32,false><<<dim3(nt64,2), 256, 0, stream>>>(
      h, W2l, b2l, W2r, b2r, xl, xr, n, nullptr, nullptr, nullptr, nullptr, 0, 0);
  edge_head_kernel<<<nq*8, 256, 0, stream>>>(xl, xr, att2, indptr, csr, part, n);
  head_reduce_kernel<<<nrc, 256, 0, stream>>>(part, bias2, (float*)d_out, n, 0);
}

// Round 6
// 302.737 us; speedup vs baseline: 1.7382x; 1.7382x over previous
//
#include <hip/hip_runtime.h>
#include <math.h>

// GATv2 2-layer: N=50000, E=800000, HEADS=8, C=32, ODIM=256, IN_C=64
#define HEADS 8
#define CDIM 32
#define ODIM 256
#define BKT_SHIFT 7              // 128 nodes per bucket
#define CHUNK 2048               // edges per histogram chunk

typedef _Float16 h2 __attribute__((ext_vector_type(2)));
typedef _Float16 h4 __attribute__((ext_vector_type(4)));
typedef _Float16 h8 __attribute__((ext_vector_type(8)));
typedef float f32x4 __attribute__((ext_vector_type(4)));
typedef unsigned long long u64;
union H4 { h4 v; h2 p[2]; u64 u; };

#if __has_builtin(__builtin_amdgcn_fdot2)
#define FDOT2(a,b,c) __builtin_amdgcn_fdot2((a),(b),(c),false)
#else
static __device__ __forceinline__ float fdot2_sw(h2 a, h2 b, float c){
  return fmaf((float)a.x, (float)b.x, fmaf((float)a.y, (float)b.y, c));
}
#define FDOT2(a,b,c) fdot2_sw((a),(b),(c))
#endif

__device__ __forceinline__ float lrelu(float v, float s){ return fmaxf(v, s*v); }

// ---- one-shot W fp32->fp16 (removes per-K-step cvt VALU from gemm; R6) ----
__global__ __launch_bounds__(256) void wcvt_kernel(
    const float* __restrict__ W1l, const float* __restrict__ W1r,
    const float* __restrict__ W2l, const float* __restrict__ W2r,
    _Float16* __restrict__ w1lh, _Float16* __restrict__ w1rh,
    _Float16* __restrict__ w2lh, _Float16* __restrict__ w2rh){
  int i = (blockIdx.x*256 + threadIdx.x)*4;   // 49152 floats total, grid exact
  const float* s; _Float16* d; int off;
  if (i < 16384)      { s = W1l; d = w1lh; off = i; }
  else if (i < 32768) { s = W1r; d = w1rh; off = i - 16384; }
  else if (i < 40960) { s = W2l; d = w2lh; off = i - 32768; }
  else                { s = W2r; d = w2rh; off = i - 40960; }
  float4 v = *(const float4*)(s + off);
  *(h4*)(d + off) = (h4){(_Float16)v.x, (_Float16)v.y, (_Float16)v.z, (_Float16)v.w};
}

// ================= atomic-free CSR build (bucket counting sort) =================
// R2: 800K device-scope atomicAdd = 72us floor -> LDS-only 5-pass sort (R3),
// hist fused into gemm1 grid (R4).

// pass 2: per-bucket exclusive scan over chunks (hist -> offs in-place)
__global__ __launch_bounds__(512) void csr_offs_kernel(
    int* __restrict__ hist, int* __restrict__ btotal, int NB, int B){
  __shared__ int s[512];
  int b = blockIdx.x, t = threadIdx.x;
  int v = (t < NB) ? hist[t*B + b] : 0;
  s[t] = v;
  __syncthreads();
  for (int off=1; off<512; off<<=1){
    int u = (t >= off) ? s[t-off] : 0;
    __syncthreads(); s[t] += u; __syncthreads();
  }
  int excl = s[t] - v;
  if (t < NB) hist[t*B + b] = excl;      // becomes offs[chunk][bucket]
  if (t == NB-1) btotal[b] = excl + v;
}

// pass 2b: bucket bases (exclusive scan of btotal, one block; B <= 512)
__global__ __launch_bounds__(512) void csr_base_kernel(
    const int* __restrict__ btotal, int* __restrict__ base, int B){
  __shared__ int s[512];
  int t = threadIdx.x;
  int v = (t < B) ? btotal[t] : 0;
  s[t] = v;
  __syncthreads();
  for (int off=1; off<512; off<<=1){
    int u = (t >= off) ? s[t-off] : 0;
    __syncthreads(); s[t] += u; __syncthreads();
  }
  if (t < B) base[t] = s[t] - v;
  if (t == B-1) base[B] = s[t];          // total valid edges
}

// pass 3: deterministic scatter to bucket-major packed array (no atomics)
__global__ __launch_bounds__(256) void csr_scatter_kernel(
    const int* __restrict__ src, const int* __restrict__ dst,
    const int* __restrict__ rank, const int* __restrict__ offs,
    const int* __restrict__ base, int* __restrict__ bpack, int e, int B){
  int t = threadIdx.x, k = blockIdx.x;
  int base_i = k*CHUNK;
#pragma unroll
  for (int j = 0; j < CHUNK/256; ++j){
    int i = base_i + j*256 + t;
    if (i < e){
      int r = rank[i];
      if (r >= 0){
        int d = dst[i], s = src[i];
        int b = d >> BKT_SHIFT;
        int pos = base[b] + offs[k*B + b] + r;
        bpack[pos] = (s << BKT_SHIFT) | (d & 127);   // s<2^16 -> fits 23 bits
      }
    }
  }
}

// pass 4: per-bucket counting sort -> csr (sequential writes) + indptr
__global__ __launch_bounds__(256) void csr_sort_kernel(
    const int* __restrict__ bpack, const int* __restrict__ base,
    int* __restrict__ csr, int* __restrict__ indptr, int n, int B){
  __shared__ int lh[128], cur[128], ss[128];
  int b = blockIdx.x, t = threadIdx.x;
  int beg = base[b], cnt = base[b+1] - beg;
  if (t < 128) lh[t] = 0;
  __syncthreads();
  for (int j = t; j < cnt; j += 256){
    int p = bpack[beg + j];
    atomicAdd(&lh[p & 127], 1);
  }
  __syncthreads();
  int v = (t < 128) ? lh[t] : 0;
  if (t < 128) ss[t] = v;
  __syncthreads();
  for (int off=1; off<128; off<<=1){
    int u = (t >= off && t < 128) ? ss[t-off] : 0;
    __syncthreads();
    if (t < 128) ss[t] += u;
    __syncthreads();
  }
  if (t < 128){
    int excl = ss[t] - v;
    cur[t] = excl;
    int node = (b << BKT_SHIFT) + t;
    if (node <= n) indptr[node] = beg + excl;   // node==n covered by last bucket
  }
  __syncthreads();
  for (int j = t; j < cnt; j += 256){
    int p = bpack[beg + j];
    int lpos = atomicAdd(&cur[p & 127], 1);
    csr[beg + lpos] = p >> BKT_SHIFT;
  }
}

// ---------------- MFMA GEMM: out[n,512] = X[n,K] * [Wl;Wr]^T + [bl;br] ----------------
// v_mfma_f32_16x16x32_f16; A=W fp16 (rows=channels, PREcvt'd by wcvt -> one 16B
// h8 load per frag, zero cvt VALU), B=X (cols=nodes). R6: 512-thread block =
// 8 waves x 64ch covers ALL 512 outputs -> X staged ONCE (R4 staged twice).
// C/D frag: col=lane&15 (node), row=(lane>>4)*4+reg (channel) -> one h4 store.
// FUSE_HIST: y==1 slice (x < NB) runs the CSR bucket histogram concurrently.
template<int K, bool FUSE_HIST>
__global__ __launch_bounds__(512) void gemm_mfma(const float* __restrict__ X,
    const _Float16* __restrict__ Wlh, const float* __restrict__ bl,
    const _Float16* __restrict__ Wrh, const float* __restrict__ br,
    _Float16* __restrict__ outl, _Float16* __restrict__ outr, int n,
    const int* __restrict__ src, const int* __restrict__ dst,
    int* __restrict__ rank, int* __restrict__ hist, int e, int B){
  if (FUSE_HIST && blockIdx.y == 1){
    int k = blockIdx.x;
    int NB = (e + CHUNK-1)/CHUNK;
    if (k >= NB) return;
    __shared__ int lh[512];
    int t = threadIdx.x;
    if (t < 512) lh[t] = 0;   // B <= 512
    __syncthreads();
    int base_i = k*CHUNK;
#pragma unroll
    for (int j = 0; j < CHUNK/512; ++j){
      int i = base_i + j*512 + t;
      if (i < e){
        int s = src[i], d = dst[i];
        int r = -1;
        if (s != d) r = atomicAdd(&lh[d>>BKT_SHIFT], 1);  // self-loops masked
        rank[i] = r;
      }
    }
    __syncthreads();
    for (int b = t; b < B; b += 512) hist[k*B + b] = lh[b];
    return;
  }
  const int KP = K + 8;
  __shared__ __align__(16) _Float16 Xs[64*(K+8)];
  int t = threadIdx.x;
  int n0 = blockIdx.x*64;

  // stage X tile once, fp32 -> fp16 (nt: X is a single-use stream)
  for (int idx = t; idx < 64*(K/4); idx += 512){
    int row = idx/(K/4), c = (idx%(K/4))*4;
    int node = n0 + row; if (node >= n) node = n-1;   // clamp; stores guarded
    f32x4 xv = __builtin_nontemporal_load((const f32x4*)(X + (size_t)node*K + c));
    *(h4*)(Xs + row*KP + c) = (h4){(_Float16)xv[0], (_Float16)xv[1],
                                   (_Float16)xv[2], (_Float16)xv[3]};
  }
  __syncthreads();

  int wave = t >> 6, lane = t & 63;
  int co = wave*64;                        // global channel base (0..511)
  const _Float16* W = (co < 256) ? Wlh : Wrh;
  const float* Bv   = (co < 256) ? bl : br;
  _Float16* outp    = (co < 256) ? outl : outr;
  int lco = co & 255;
  int lr = lane & 15, lg = lane >> 4;

  f32x4 acc[4][4];
#pragma unroll
  for (int c = 0; c < 4; ++c)
#pragma unroll
    for (int m = 0; m < 4; ++m) acc[c][m] = (f32x4){0.f, 0.f, 0.f, 0.f};

#pragma unroll
  for (int ks = 0; ks < K/32; ++ks){
    int k0 = ks*32 + lg*8;
    h8 a[4], b[4];
#pragma unroll
    for (int c = 0; c < 4; ++c)                  // A: W[ch][k0..k0+7], one 16B load
      a[c] = *(const h8*)(W + (size_t)(lco + c*16 + lr)*K + k0);
#pragma unroll
    for (int m = 0; m < 4; ++m)                  // B: Xs[node][k0..k0+7]
      b[m] = *(const h8*)(Xs + (m*16 + lr)*KP + k0);
#pragma unroll
    for (int c = 0; c < 4; ++c)
#pragma unroll
      for (int m = 0; m < 4; ++m)
        acc[c][m] = __builtin_amdgcn_mfma_f32_16x16x32_f16(a[c], b[m], acc[c][m], 0, 0, 0);
  }

  // epilogue: frag (c,m): lane -> node n0+m*16+(lane&15), channels lco+c*16+lg*4+[0..3]
#pragma unroll
  for (int c = 0; c < 4; ++c){
    int ch = lco + c*16 + lg*4;
    float4 bb = *(const float4*)(Bv + ch);
#pragma unroll
    for (int m = 0; m < 4; ++m){
      int node = n0 + m*16 + lr;
      if (node < n){
        h4 o = {(_Float16)(acc[c][m][0] + bb.x), (_Float16)(acc[c][m][1] + bb.y),
                (_Float16)(acc[c][m][2] + bb.z), (_Float16)(acc[c][m][3] + bb.w)};
        *(h4*)(outp + (size_t)node*ODIM + ch) = o;
      }
    }
  }
}

// ---------------- fused edge softmax + aggregate, one wave per node ----------------
// R4-proven structure: adjacency loaded once per 64-edge chunk (256B wave read
// + shfl broadcast), 2 edges/iter, 4-deep prefetch ring. R6: nontemporal hints
// on the single-use streams (xr row, csr chunk, output) so they stop evicting
// the gather-hot xl lines from L2 (edge kernel is fetch-path-bound at ~2.8TB/s,
// FETCH ~= 8 XCD x 25.6MB full-array streaming).
__global__ __launch_bounds__(256) void edge_kernel(
    const _Float16* __restrict__ xl, const _Float16* __restrict__ xr,
    const float* __restrict__ att, const float* __restrict__ bias,
    const int* __restrict__ indptr, const int* __restrict__ csr_src,
    float* __restrict__ out, int n, int act)
{
  int wid = blockIdx.x*4 + (threadIdx.x >> 6);
  if (wid >= n) return;
  int lane = threadIdx.x & 63;
  const float LOG2E = 1.44269504088896341f;

  float4 attf = *(const float4*)(att + 4*lane);
  h2 at0 = (h2){(_Float16)(attf.x*LOG2E), (_Float16)(attf.y*LOG2E)};
  h2 at1 = (h2){(_Float16)(attf.z*LOG2E), (_Float16)(attf.w*LOG2E)};
  const h2 c02 = {(_Float16)0.2f, (_Float16)0.2f};

  H4 xrh; xrh.u = __builtin_nontemporal_load((const u64*)(xr + (size_t)wid*ODIM + 4*lane));
  H4 self; self.v = *(const h4*)(xl + (size_t)wid*ODIM + 4*lane);

  auto score = [&](const H4& c)->float{
    h2 t0 = c.p[0] + xrh.p[0];
    h2 t1 = c.p[1] + xrh.p[1];
    h2 q0 = __builtin_elementwise_max(t0, t0 * c02);
    h2 q1 = __builtin_elementwise_max(t1, t1 * c02);
    float d = FDOT2(q0, at0, FDOT2(q1, at1, 0.f));
    d += __shfl_xor(d, 1);   // reduce over the 8 lanes of this head
    d += __shfl_xor(d, 2);
    d += __shfl_xor(d, 4);
    return d;
  };

  // self-loop seeds the accumulator
  float w0 = exp2f(score(self));
  float denom = w0;
  float4 acc;
  acc.x = w0 * (float)self.v.x;
  acc.y = w0 * (float)self.v.y;
  acc.z = w0 * (float)self.v.z;
  acc.w = w0 * (float)self.v.w;

  int beg = __builtin_amdgcn_readfirstlane(indptr[wid]);
  int end = __builtin_amdgcn_readfirstlane(indptr[wid+1]);
  int cnt = end - beg;

#define GATHER(j) (*(const h4*)(xl + (size_t)((unsigned)__shfl(sidx,(j)))*ODIM + 4*lane))
  for (int cb = 0; cb < cnt; cb += 64){          // 64-edge chunks (deg>64 safe)
    int ccnt = min(cnt - cb, 64);
    int sidx = (lane < ccnt) ? __builtin_nontemporal_load(csr_src + beg + cb + lane) : 0;
    H4 r0, r1, r2, r3;
    r0.v = (h4){}; r1.v = (h4){}; r2.v = (h4){}; r3.v = (h4){};
    if (ccnt > 0) r0.v = GATHER(0);
    if (ccnt > 1) r1.v = GATHER(1);
    if (ccnt > 2) r2.v = GATHER(2);
    if (ccnt > 3) r3.v = GATHER(3);
#pragma unroll 2
    for (int k = 0; k < ccnt; k += 2){
      H4 e0 = r0, e1 = r1;
      r0 = r2; r1 = r3;
      if (k+4 < ccnt) r2.v = GATHER(k+4);        // prefetch 4 edges ahead
      if (k+5 < ccnt) r3.v = GATHER(k+5);
      float s0 = score(e0);
      float s1 = score(e1);
      float pe0 = exp2f(s0);
      float pe1 = (k+1 < ccnt) ? exp2f(s1) : 0.f;  // tail guard (e1 may be stale)
      denom += pe0 + pe1;
      acc.x = fmaf(pe0, (float)e0.v.x, fmaf(pe1, (float)e1.v.x, acc.x));
      acc.y = fmaf(pe0, (float)e0.v.y, fmaf(pe1, (float)e1.v.y, acc.y));
      acc.z = fmaf(pe0, (float)e0.v.z, fmaf(pe1, (float)e1.v.z, acc.z));
      acc.w = fmaf(pe0, (float)e0.v.w, fmaf(pe1, (float)e1.v.w, acc.w));
    }
  }
#undef GATHER

  float inv = 1.f/denom;
  float vx = acc.x*inv, vy = acc.y*inv, vz = acc.z*inv, vw = acc.w*inv;
  // mean over heads: sum lanes {l, l^8, l^16, l^32}
  vx += __shfl_xor(vx, 8);  vx += __shfl_xor(vx, 16);  vx += __shfl_xor(vx, 32);
  vy += __shfl_xor(vy, 8);  vy += __shfl_xor(vy, 16);  vy += __shfl_xor(vy, 32);
  vz += __shfl_xor(vz, 8);  vz += __shfl_xor(vz, 16);  vz += __shfl_xor(vz, 32);
  vw += __shfl_xor(vw, 8);  vw += __shfl_xor(vw, 16);  vw += __shfl_xor(vw, 32);
  if (lane < 8){
    float4 bv = *(const float4*)(bias + 4*lane);
    float ox = vx*0.125f + bv.x;
    float oy = vy*0.125f + bv.y;
    float oz = vz*0.125f + bv.z;
    float ow = vw*0.125f + bv.w;
    if (act){
      ox = lrelu(ox, 0.01f); oy = lrelu(oy, 0.01f);
      oz = lrelu(oz, 0.01f); ow = lrelu(ow, 0.01f);
    }
    f32x4 ov = {ox, oy, oz, ow};
    __builtin_nontemporal_store(ov, (f32x4*)(out + (size_t)wid*CDIM + 4*lane));
  }
}

extern "C" void kernel_launch(void* const* d_in, const int* in_sizes, int n_in,
                              void* d_out, int out_size, void* d_ws, size_t ws_size,
                              hipStream_t stream){
  (void)n_in; (void)out_size; (void)ws_size;
  const float* x    = (const float*)d_in[0];
  const int*   ei   = (const int*)d_in[1];
  const float* W1l  = (const float*)d_in[2];
  const float* b1l  = (const float*)d_in[3];
  const float* W1r  = (const float*)d_in[4];
  const float* b1r  = (const float*)d_in[5];
  const float* att1 = (const float*)d_in[6];
  const float* bias1= (const float*)d_in[7];
  const float* W2l  = (const float*)d_in[8];
  const float* b2l  = (const float*)d_in[9];
  const float* W2r  = (const float*)d_in[10];
  const float* b2r  = (const float*)d_in[11];
  const float* att2 = (const float*)d_in[12];
  const float* bias2= (const float*)d_in[13];
  int n = in_sizes[0] / 64;   // 50000
  int e = in_sizes[1] / 2;    // 800000
  const int* src = ei;
  const int* dst = ei + e;

  char* ws = (char*)d_ws;
  size_t off = 0;
  auto alloc = [&](size_t bytes)->char*{
    char* p = ws + off; off += (bytes + 255) & ~(size_t)255; return p;
  };
  _Float16* xl  = (_Float16*)alloc((size_t)n*ODIM*2);  // 25.6 MB fp16
  _Float16* xr  = (_Float16*)alloc((size_t)n*ODIM*2);  // 25.6 MB fp16
  float* h      = (float*)alloc((size_t)n*CDIM*4);     // 6.4 MB layer-1 output
  int*   indptr = (int*)alloc((size_t)(n+1)*4);
  int*   rank   = (int*)alloc((size_t)e*4);
  int*   csr    = (int*)alloc((size_t)e*4);
  int*   bpack  = (int*)alloc((size_t)e*4);
  _Float16* w1lh = (_Float16*)alloc((size_t)ODIM*64*2);   // 32 KB
  _Float16* w1rh = (_Float16*)alloc((size_t)ODIM*64*2);
  _Float16* w2lh = (_Float16*)alloc((size_t)ODIM*32*2);   // 16 KB
  _Float16* w2rh = (_Float16*)alloc((size_t)ODIM*32*2);

  int NB = (e + CHUNK-1) / CHUNK;   // 391 edge chunks
  int B  = (n + 127) >> 7;          // 391 buckets of 128 nodes
  int*   hist   = (int*)alloc((size_t)NB*B*4);         // 611 KB (becomes offs)
  int*   btotal = (int*)alloc((size_t)B*4);
  int*   base   = (int*)alloc((size_t)(B+1)*4);

  int nt64 = (n + 63) / 64;         // 782

  // ---- W -> fp16 once (48 blocks, ~2us) ----
  wcvt_kernel<<<48, 256, 0, stream>>>(W1l, W1r, W2l, W2r, w1lh, w1rh, w2lh, w2rh);
  // ---- layer-1 GEMM (X staged once, 8 waves/block) + fused CSR hist (y==1) ----
  gemm_mfma<64,true><<<dim3(nt64,2), 512, 0, stream>>>(
      x, w1lh, b1l, w1rh, b1r, xl, xr, n, src, dst, rank, hist, e, B);
  // ---- rest of atomic-free CSR build ----
  csr_offs_kernel<<<B, 512, 0, stream>>>(hist, btotal, NB, B);
  csr_base_kernel<<<1, 512, 0, stream>>>(btotal, base, B);
  csr_scatter_kernel<<<NB, 256, 0, stream>>>(src, dst, rank, hist, base, bpack, e, B);
  csr_sort_kernel<<<B, 256, 0, stream>>>(bpack, base, csr, indptr, n, B);

  edge_kernel<<<(n+3)/4, 256, 0, stream>>>(xl, xr, att1, bias1, indptr, csr, h, n, 1);
  // ---- layer 2 ----
  gemm_mfma<32,false><<<dim3(nt64,1), 512, 0, stream>>>(
      h, w2lh, b2l, w2rh, b2r, xl, xr, n, nullptr, nullptr, nullptr, nullptr, 0, 0);
  edge_kernel<<<(n+3)/4, 256, 0, stream>>>(xl, xr, att2, bias2, indptr, csr, (float*)d_out, n, 0);
}